// Round 1
// baseline (1876.450 us; speedup 1.0000x reference)
//
#include <hip/hip_runtime.h>
#include <math.h>

#define N_NODES 50000
#define N_EDGES 800000
#define N_MOLS  2000

static constexpr float BN_INV_F = 0.9999950000374997f; // 1/sqrt(1+1e-5)

enum { ACT_NONE = 0, ACT_LEAKY = 1, ACT_BN_DL = 2 };

// ---------------- counting sort of edges by dst ----------------

__global__ void hist_kernel(const int* __restrict__ ei, int* __restrict__ cnt) {
    int e = blockIdx.x * 256 + threadIdx.x;
    if (e < N_EDGES) atomicAdd(&cnt[ei[N_EDGES + e]], 1);
}

__global__ __launch_bounds__(1024) void scan_kernel(const int* __restrict__ cnt,
                                                    int* __restrict__ start,
                                                    int* __restrict__ cursor) {
    __shared__ int sd[1024];
    __shared__ int s_run;
    if (threadIdx.x == 0) s_run = 0;
    __syncthreads();
    for (int base = 0; base < N_NODES; base += 1024) {
        int i = base + threadIdx.x;
        int v = (i < N_NODES) ? cnt[i] : 0;
        sd[threadIdx.x] = v;
        __syncthreads();
        for (int off = 1; off < 1024; off <<= 1) {
            int t = (threadIdx.x >= off) ? sd[threadIdx.x - off] : 0;
            __syncthreads();
            sd[threadIdx.x] += t;
            __syncthreads();
        }
        int incl = sd[threadIdx.x];
        int run = s_run;
        if (i < N_NODES) {
            int ex = run + incl - v;
            start[i] = ex;
            cursor[i] = ex;
        }
        __syncthreads();
        if (threadIdx.x == 1023) s_run = run + sd[1023];
        __syncthreads();
    }
    if (threadIdx.x == 0) start[N_NODES] = s_run;
}

__global__ void scatter_kernel(const int* __restrict__ ei, int* __restrict__ cursor,
                               int* __restrict__ order) {
    int e = blockIdx.x * 256 + threadIdx.x;
    if (e < N_EDGES) {
        int d = ei[N_EDGES + e];
        int pos = atomicAdd(&cursor[d], 1);
        order[pos] = e;
    }
}

// ---------------- per-node gather-aggregate of edge messages ----------------
// t[v][f] = hin[v][f] + sum_{e: dst=v} relu(hin[src_e][f] + (ea_e @ eW + eb)[f])

template<int D>
__global__ void edge_agg_kernel(const float* __restrict__ hin, int ld_in,
                                const float* __restrict__ ea,
                                const int* __restrict__ ei,       // src = ei[0..E)
                                const int* __restrict__ order,
                                const int* __restrict__ start,
                                const float* __restrict__ eW,     // [16, D]
                                const float* __restrict__ eb,     // [D]
                                float* __restrict__ tout) {
    int v = blockIdx.x;
    int f = threadIdx.x;
    float w[16];
#pragma unroll
    for (int k = 0; k < 16; ++k) w[k] = eW[k * D + f];
    float ebf = eb[f];
    int s0 = start[v], s1 = start[v + 1];
    float acc = 0.f;
    for (int idx = s0; idx < s1; ++idx) {
        int e = order[idx];
        int s = ei[e];
        const float4* ap = (const float4*)(ea + (size_t)e * 16);
        float4 a0 = ap[0], a1 = ap[1], a2 = ap[2], a3 = ap[3];
        float ev = ebf;
        ev += a0.x * w[0]  + a0.y * w[1]  + a0.z * w[2]  + a0.w * w[3];
        ev += a1.x * w[4]  + a1.y * w[5]  + a1.z * w[6]  + a1.w * w[7];
        ev += a2.x * w[8]  + a2.y * w[9]  + a2.z * w[10] + a2.w * w[11];
        ev += a3.x * w[12] + a3.y * w[13] + a3.z * w[14] + a3.w * w[15];
        float m = hin[(size_t)s * ld_in + f] + ev;
        acc += fmaxf(m, 0.f);
    }
    tout[(size_t)v * D + f] = hin[(size_t)v * ld_in + f] + acc;
}

// ---------------- fp32 tiled linear: C = act(A @ W + b) ----------------
// BM=16 rows/block, 256 threads, each thread 4 cols x RPT rows.

template<int DIN, int DOUT, int ACT>
__global__ __launch_bounds__(256) void lin_kernel(
        const float* __restrict__ A, int lda,
        const float* __restrict__ W,      // [DIN, DOUT]
        const float* __restrict__ bias,   // [DOUT]
        const float* __restrict__ gamma,
        const float* __restrict__ beta,
        float* __restrict__ C, int ldc) {
    constexpr int BM = 16;
    constexpr int KC = 32;
    constexpr int NCG = DOUT / 4;   // col groups of 4
    constexpr int NG  = 256 / NCG;  // row groups
    constexpr int RPT = BM / NG;    // rows per thread
    __shared__ float As[KC][BM + 4];  // stride 20 floats
    const int col4 = (threadIdx.x % NCG) * 4;
    const int rg   = threadIdx.x / NCG;
    const int row0 = blockIdx.x * BM;
    float acc[RPT][4];
#pragma unroll
    for (int i = 0; i < RPT; ++i)
#pragma unroll
        for (int j = 0; j < 4; ++j) acc[i][j] = 0.f;

    for (int k0 = 0; k0 < DIN; k0 += KC) {
        __syncthreads();
        for (int t = threadIdx.x; t < BM * KC; t += 256) {
            int k = t & (KC - 1);
            int r = t >> 5;
            As[k][r] = A[(size_t)(row0 + r) * lda + k0 + k];
        }
        __syncthreads();
#pragma unroll
        for (int k = 0; k < KC; ++k) {
            const float4 wv = *(const float4*)&W[(size_t)(k0 + k) * DOUT + col4];
#pragma unroll
            for (int i = 0; i < RPT; ++i) {
                float av = As[k][rg * RPT + i];
                acc[i][0] += av * wv.x;
                acc[i][1] += av * wv.y;
                acc[i][2] += av * wv.z;
                acc[i][3] += av * wv.w;
            }
        }
    }
#pragma unroll
    for (int i = 0; i < RPT; ++i) {
        int row = row0 + rg * RPT + i;
#pragma unroll
        for (int j = 0; j < 4; ++j) {
            int c = col4 + j;
            float v = acc[i][j] + bias[c];
            if (ACT == ACT_BN_DL) {
                v = gamma[c] * (v * BN_INV_F) + beta[c];
                v = v > 0.f ? v : 1e-4f * v;   // leaky(leaky(v))
            } else if (ACT == ACT_LEAKY) {
                v = v > 0.f ? v : 0.01f * v;
            }
            C[(size_t)row * ldc + c] = v;
        }
    }
}

// ---------------- pooling ----------------

__global__ void pool_add_kernel(const float* __restrict__ concat, const int* __restrict__ batch,
                                float* __restrict__ pool) {
    int idx = blockIdx.x * 256 + threadIdx.x;
    if (idx >= N_NODES * 128) return;
    int n = idx >> 7, f = idx & 127;
    atomicAdd(&pool[batch[n] * 128 + f], concat[(size_t)n * 640 + 384 + f]);
}

__global__ void pool_gather_kernel(float* __restrict__ concat, const int* __restrict__ batch,
                                   const float* __restrict__ pool) {
    int idx = blockIdx.x * 256 + threadIdx.x;
    if (idx >= N_NODES * 128) return;
    int n = idx >> 7, f = idx & 127;
    concat[(size_t)n * 640 + 512 + f] = pool[batch[n] * 128 + f];
}

// ---------------- final 256 -> 1 + sigmoid ----------------

__global__ __launch_bounds__(256) void final_kernel(const float* __restrict__ A,
                                                    const float* __restrict__ fW,
                                                    const float* __restrict__ fb,
                                                    float* __restrict__ out) {
    int wave = threadIdx.x >> 6;
    int lane = threadIdx.x & 63;
    int row = blockIdx.x * 4 + wave;
    const float* ar = A + (size_t)row * 256;
    float p = 0.f;
#pragma unroll
    for (int i = 0; i < 4; ++i) {
        int k = lane + i * 64;
        p += ar[k] * fW[k];
    }
#pragma unroll
    for (int off = 32; off >= 1; off >>= 1) p += __shfl_xor(p, off, 64);
    if (lane == 0) out[row] = 1.f / (1.f + expf(-(p + fb[0])));
}

// ---------------- launch ----------------

extern "C" void kernel_launch(void* const* d_in, const int* in_sizes, int n_in,
                              void* d_out, int out_size, void* d_ws, size_t ws_size,
                              hipStream_t stream) {
    const float* x     = (const float*)d_in[0];
    const int*   ei    = (const int*)d_in[1];
    const float* ea    = (const float*)d_in[2];
    const int*   batch = (const int*)d_in[3];
    const float* c1W   = (const float*)d_in[4];
    const float* c1b   = (const float*)d_in[5];
    const float* c1g   = (const float*)d_in[6];
    const float* c1be  = (const float*)d_in[7];
    const float* c1eW  = (const float*)d_in[8];
    const float* c1eb  = (const float*)d_in[9];
    const float* cW    = (const float*)d_in[10];
    const float* cb    = (const float*)d_in[11];
    const float* cg    = (const float*)d_in[12];
    const float* cbe   = (const float*)d_in[13];
    const float* ceW   = (const float*)d_in[14];
    const float* ceb   = (const float*)d_in[15];
    const float* cls1W = (const float*)d_in[16];
    const float* cls1b = (const float*)d_in[17];
    const float* clsW  = (const float*)d_in[18];
    const float* clsb  = (const float*)d_in[19];
    const float* fW    = (const float*)d_in[20];
    const float* fb    = (const float*)d_in[21];
    float* out = (float*)d_out;

    char* ws = (char*)d_ws;
    size_t off = 0;
    auto alloc = [&](size_t bytes) {
        void* p = ws + off;
        off += (bytes + 255) & ~(size_t)255;
        return p;
    };
    int*   order  = (int*)alloc((size_t)N_EDGES * 4);
    int*   startA = (int*)alloc((size_t)(N_NODES + 1) * 4);
    int*   cursor = (int*)alloc((size_t)N_NODES * 4);
    int*   cnt    = (int*)alloc((size_t)N_NODES * 4);
    float* h1     = (float*)alloc((size_t)N_NODES * 128 * 4);   // 25.6 MB
    float* tbuf   = (float*)alloc((size_t)N_NODES * 128 * 4);   // 25.6 MB (adjacent to h1)
    float* pool   = (float*)alloc((size_t)N_MOLS * 128 * 4);
    float* concat = (float*)alloc((size_t)N_NODES * 640 * 4);   // 128 MB
    // overlays (lifetimes disjoint):
    float* clsA = h1;      // spans h1+tbuf = 51.2 MB, used after conv layers done
    float* clsB = concat;  // concat not needed after cls1

    hipMemsetAsync(cnt, 0, (size_t)N_NODES * 4, stream);
    hipMemsetAsync(pool, 0, (size_t)N_MOLS * 128 * 4, stream);

    hist_kernel<<<(N_EDGES + 255) / 256, 256, 0, stream>>>(ei, cnt);
    scan_kernel<<<1, 1024, 0, stream>>>(cnt, startA, cursor);
    scatter_kernel<<<(N_EDGES + 255) / 256, 256, 0, stream>>>(ei, cursor, order);

    // conv1: x [N,64] -> h1 [N,128]
    edge_agg_kernel<64><<<N_NODES, 64, 0, stream>>>(x, 64, ea, ei, order, startA, c1eW, c1eb, tbuf);
    lin_kernel<64, 128, ACT_BN_DL><<<N_NODES / 16, 256, 0, stream>>>(
        tbuf, 64, c1W, c1b, c1g, c1be, h1, 128);

    // conv layers 0..3: write each output into its concat slice
    for (int i = 0; i < 4; ++i) {
        const float* hin = (i == 0) ? h1 : (concat + (size_t)(i - 1) * 128);
        int ld = (i == 0) ? 128 : 640;
        edge_agg_kernel<128><<<N_NODES, 128, 0, stream>>>(
            hin, ld, ea, ei, order, startA,
            ceW + (size_t)i * 16 * 128, ceb + (size_t)i * 128, tbuf);
        lin_kernel<128, 128, ACT_BN_DL><<<N_NODES / 16, 256, 0, stream>>>(
            tbuf, 128, cW + (size_t)i * 128 * 128, cb + i * 128,
            cg + i * 128, cbe + i * 128, concat + (size_t)i * 128, 640);
    }

    // global add pool of last layer (concat cols 384..511) -> concat cols 512..639
    pool_add_kernel<<<(N_NODES * 128 + 255) / 256, 256, 0, stream>>>(concat, batch, pool);
    pool_gather_kernel<<<(N_NODES * 128 + 255) / 256, 256, 0, stream>>>(concat, batch, pool);

    // classifier
    lin_kernel<640, 256, ACT_NONE><<<N_NODES / 16, 256, 0, stream>>>(
        concat, 640, cls1W, cls1b, nullptr, nullptr, clsA, 256);
    lin_kernel<256, 256, ACT_LEAKY><<<N_NODES / 16, 256, 0, stream>>>(
        clsA, 256, clsW, clsb, nullptr, nullptr, clsB, 256);
    lin_kernel<256, 256, ACT_LEAKY><<<N_NODES / 16, 256, 0, stream>>>(
        clsB, 256, clsW + 256 * 256, clsb + 256, nullptr, nullptr, clsA, 256);
    final_kernel<<<N_NODES / 4, 256, 0, stream>>>(clsA, fW, fb, out);
}

// Round 3
// 1274.424 us; speedup vs baseline: 1.4724x; 1.4724x over previous
//
#include <hip/hip_runtime.h>
#include <hip/hip_bf16.h>
#include <math.h>

#define N_NODES 50000
#define N_EDGES 800000
#define N_MOLS  2000

static constexpr float BN_INV_F = 0.9999950000374997f; // 1/sqrt(1+1e-5)

enum { ACT_NONE = 0, ACT_LEAKY = 1, ACT_BN_DL = 2 };

typedef float f32x4 __attribute__((ext_vector_type(4)));
typedef short bf16x8 __attribute__((ext_vector_type(8)));

// ---------------- counting sort of edges by dst ----------------

__global__ void hist_kernel(const int* __restrict__ ei, int* __restrict__ cnt) {
    int e = blockIdx.x * 256 + threadIdx.x;
    if (e < N_EDGES) atomicAdd(&cnt[ei[N_EDGES + e]], 1);
}

__global__ __launch_bounds__(1024) void scan1_kernel(const int* __restrict__ cnt,
                                                     int* __restrict__ incl,
                                                     int* __restrict__ bsum) {
    __shared__ int sd[1024];
    int i = blockIdx.x * 1024 + threadIdx.x;
    int v = (i < N_NODES) ? cnt[i] : 0;
    sd[threadIdx.x] = v;
    __syncthreads();
    for (int off = 1; off < 1024; off <<= 1) {
        int t = (threadIdx.x >= off) ? sd[threadIdx.x - off] : 0;
        __syncthreads();
        sd[threadIdx.x] += t;
        __syncthreads();
    }
    incl[i] = sd[threadIdx.x];
    if (threadIdx.x == 1023) bsum[blockIdx.x] = sd[1023];
}

__global__ void scan2_kernel(const int* __restrict__ bsum, int* __restrict__ bex,
                             int* __restrict__ start, int nblk) {
    if (threadIdx.x == 0) {
        int run = 0;
        for (int b = 0; b < nblk; ++b) { bex[b] = run; run += bsum[b]; }
        start[N_NODES] = run;
    }
}

__global__ __launch_bounds__(1024) void scan3_kernel(const int* __restrict__ cnt,
                                                     const int* __restrict__ incl,
                                                     const int* __restrict__ bex,
                                                     int* __restrict__ start,
                                                     int* __restrict__ cursor) {
    int i = blockIdx.x * 1024 + threadIdx.x;
    if (i < N_NODES) {
        int s = bex[blockIdx.x] + incl[i] - cnt[i];
        start[i] = s;
        cursor[i] = s;
    }
}

__global__ void scatter_kernel(const int* __restrict__ ei, int* __restrict__ cursor,
                               int* __restrict__ order) {
    int e = blockIdx.x * 256 + threadIdx.x;
    if (e < N_EDGES) {
        int d = ei[N_EDGES + e];
        int pos = atomicAdd(&cursor[d], 1);
        order[pos] = e;
    }
}

// ---------------- weight convert + transpose: W[K][Nc] f32 -> Wt[Nc][K] bf16 ----

__global__ void cvt_t_kernel(const float* __restrict__ src, __hip_bfloat16* __restrict__ dst,
                             int K, int Nc) {
    int o = blockIdx.x * 256 + threadIdx.x;
    if (o >= K * Nc) return;
    int n = o / K, k = o - n * K;
    dst[o] = __float2bfloat16(src[(size_t)k * Nc + n]);
}

// ---------------- per-node gather-aggregate of edge messages ----------------
// t[v][f] = hin[v][f] + sum_{e: dst=v} relu(hin[src_e][f] + (ea_e @ eW + eb)[f])

template<int D, bool BF16IN>
__global__ void edge_agg_kernel(const void* __restrict__ hin_, int ld_in,
                                const float* __restrict__ ea,
                                const int* __restrict__ ei,       // src = ei[0..E)
                                const int* __restrict__ order,
                                const int* __restrict__ start,
                                const float* __restrict__ eW,     // [16, D]
                                const float* __restrict__ eb,     // [D]
                                __hip_bfloat16* __restrict__ tout) {
    const float* hin_f = (const float*)hin_;
    const __hip_bfloat16* hin_b = (const __hip_bfloat16*)hin_;
    int v = blockIdx.x;
    int f = threadIdx.x;
    float w[16];
#pragma unroll
    for (int k = 0; k < 16; ++k) w[k] = eW[k * D + f];
    float ebf = eb[f];
    int s0 = start[v], s1 = start[v + 1];
    float acc = 0.f;
    for (int idx = s0; idx < s1; ++idx) {
        int e = order[idx];
        int s = ei[e];
        const float4* ap = (const float4*)(ea + (size_t)e * 16);
        float4 a0 = ap[0], a1 = ap[1], a2 = ap[2], a3 = ap[3];
        float ev = ebf;
        ev += a0.x * w[0]  + a0.y * w[1]  + a0.z * w[2]  + a0.w * w[3];
        ev += a1.x * w[4]  + a1.y * w[5]  + a1.z * w[6]  + a1.w * w[7];
        ev += a2.x * w[8]  + a2.y * w[9]  + a2.z * w[10] + a2.w * w[11];
        ev += a3.x * w[12] + a3.y * w[13] + a3.z * w[14] + a3.w * w[15];
        float hs = BF16IN ? __bfloat162float(hin_b[(size_t)s * ld_in + f])
                          : hin_f[(size_t)s * ld_in + f];
        acc += fmaxf(hs + ev, 0.f);
    }
    float hv = BF16IN ? __bfloat162float(hin_b[(size_t)v * ld_in + f])
                      : hin_f[(size_t)v * ld_in + f];
    tout[(size_t)v * D + f] = __float2bfloat16(hv + acc);
}

// ---------------- bf16 MFMA linear: C = act(A @ W + b) ----------------
// 4 waves/block; each wave computes 64 rows x 64 cols (4x4 tiles of 16x16).
// B (weights, pre-transposed Wt[DOUT][DIN] bf16) held in registers per K-chunk,
// loaded straight from global (L2-resident). A fragments loaded from global.

template<int DIN, int DOUT, int KCHUNK, int ACT>
__global__ __launch_bounds__(256) void mfma_lin_kernel(
        const __hip_bfloat16* __restrict__ A, int lda,
        const __hip_bfloat16* __restrict__ Wt,  // [DOUT][DIN]
        const float* __restrict__ bias,
        const float* __restrict__ gamma,
        const float* __restrict__ beta,
        __hip_bfloat16* __restrict__ C, int ldc) {
    constexpr int WCOLS = DOUT / 64;     // waves along cols
    constexpr int WROWS = 4 / WCOLS;     // waves along rows
    constexpr int BROWS = WROWS * 64;    // rows per block
    constexpr int NKS = KCHUNK / 32;     // k-steps per chunk
    constexpr int NCH = DIN / KCHUNK;    // chunks
    const int wid = threadIdx.x >> 6, lane = threadIdx.x & 63;
    const int wr = wid / WCOLS, wc = wid % WCOLS;
    const int row_base = blockIdx.x * BROWS + wr * 64;
    const int col0 = wc * 64;
    const int lrow = lane & 15;
    const int lk = (lane >> 4) * 8;

    f32x4 acc[4][4];
#pragma unroll
    for (int i = 0; i < 4; ++i)
#pragma unroll
        for (int j = 0; j < 4; ++j) acc[i][j] = (f32x4){0.f, 0.f, 0.f, 0.f};

    for (int ch = 0; ch < NCH; ++ch) {
        const int kc = ch * KCHUNK;
        bf16x8 b[4][NKS];
#pragma unroll
        for (int ct = 0; ct < 4; ++ct)
#pragma unroll
            for (int ks = 0; ks < NKS; ++ks)
                b[ct][ks] = *reinterpret_cast<const bf16x8*>(
                    &Wt[(size_t)(col0 + ct * 16 + lrow) * DIN + kc + ks * 32 + lk]);
#pragma unroll
        for (int rt = 0; rt < 4; ++rt) {
            int arow = row_base + rt * 16 + lrow;
            arow = arow < N_NODES ? arow : N_NODES - 1;
            bf16x8 a[NKS];
#pragma unroll
            for (int ks = 0; ks < NKS; ++ks)
                a[ks] = *reinterpret_cast<const bf16x8*>(
                    &A[(size_t)arow * lda + kc + ks * 32 + lk]);
#pragma unroll
            for (int ct = 0; ct < 4; ++ct)
#pragma unroll
                for (int ks = 0; ks < NKS; ++ks)
                    acc[rt][ct] = __builtin_amdgcn_mfma_f32_16x16x32_bf16(
                        a[ks], b[ct][ks], acc[rt][ct], 0, 0, 0);
        }
    }

    // epilogue: C[row=(lane>>4)*4+r][col=lane&15] per 16x16 tile
#pragma unroll
    for (int rt = 0; rt < 4; ++rt) {
        int r0 = row_base + rt * 16 + (lane >> 4) * 4;
#pragma unroll
        for (int ct = 0; ct < 4; ++ct) {
            int c = col0 + ct * 16 + lrow;
            float bi = bias[c];
            float ga = (ACT == ACT_BN_DL) ? gamma[c] : 0.f;
            float be = (ACT == ACT_BN_DL) ? beta[c] : 0.f;
#pragma unroll
            for (int r = 0; r < 4; ++r) {
                int row = r0 + r;
                if (row < N_NODES) {
                    float v = acc[rt][ct][r] + bi;
                    if (ACT == ACT_BN_DL) {
                        v = ga * (v * BN_INV_F) + be;
                        v = v > 0.f ? v : 1e-4f * v;   // leaky(leaky(v))
                    } else if (ACT == ACT_LEAKY) {
                        v = v > 0.f ? v : 0.01f * v;
                    }
                    C[(size_t)row * ldc + c] = __float2bfloat16(v);
                }
            }
        }
    }
}

// ---------------- pooling ----------------

__global__ void pool_add_kernel(const __hip_bfloat16* __restrict__ concat,
                                const int* __restrict__ batch,
                                float* __restrict__ pool) {
    int idx = blockIdx.x * 256 + threadIdx.x;
    if (idx >= N_NODES * 128) return;
    int n = idx >> 7, f = idx & 127;
    atomicAdd(&pool[batch[n] * 128 + f],
              __bfloat162float(concat[(size_t)n * 640 + 384 + f]));
}

__global__ void pool_gather_kernel(__hip_bfloat16* __restrict__ concat,
                                   const int* __restrict__ batch,
                                   const float* __restrict__ pool) {
    int idx = blockIdx.x * 256 + threadIdx.x;
    if (idx >= N_NODES * 128) return;
    int n = idx >> 7, f = idx & 127;
    concat[(size_t)n * 640 + 512 + f] = __float2bfloat16(pool[batch[n] * 128 + f]);
}

// ---------------- final 256 -> 1 + sigmoid ----------------

__global__ __launch_bounds__(256) void final_kernel(const __hip_bfloat16* __restrict__ A,
                                                    const float* __restrict__ fW,
                                                    const float* __restrict__ fb,
                                                    float* __restrict__ out) {
    int wave = threadIdx.x >> 6;
    int lane = threadIdx.x & 63;
    int row = blockIdx.x * 4 + wave;
    const __hip_bfloat16* ar = A + (size_t)row * 256;
    float p = 0.f;
#pragma unroll
    for (int i = 0; i < 4; ++i) {
        int k = lane + i * 64;
        p += __bfloat162float(ar[k]) * fW[k];
    }
#pragma unroll
    for (int off = 32; off >= 1; off >>= 1) p += __shfl_xor(p, off, 64);
    if (lane == 0) out[row] = 1.f / (1.f + expf(-(p + fb[0])));
}

// ---------------- launch ----------------

extern "C" void kernel_launch(void* const* d_in, const int* in_sizes, int n_in,
                              void* d_out, int out_size, void* d_ws, size_t ws_size,
                              hipStream_t stream) {
    const float* x     = (const float*)d_in[0];
    const int*   ei    = (const int*)d_in[1];
    const float* ea    = (const float*)d_in[2];
    const int*   batch = (const int*)d_in[3];
    const float* c1W   = (const float*)d_in[4];
    const float* c1b   = (const float*)d_in[5];
    const float* c1g   = (const float*)d_in[6];
    const float* c1be  = (const float*)d_in[7];
    const float* c1eW  = (const float*)d_in[8];
    const float* c1eb  = (const float*)d_in[9];
    const float* cW    = (const float*)d_in[10];
    const float* cb    = (const float*)d_in[11];
    const float* cg    = (const float*)d_in[12];
    const float* cbe   = (const float*)d_in[13];
    const float* ceW   = (const float*)d_in[14];
    const float* ceb   = (const float*)d_in[15];
    const float* cls1W = (const float*)d_in[16];
    const float* cls1b = (const float*)d_in[17];
    const float* clsW  = (const float*)d_in[18];
    const float* clsb  = (const float*)d_in[19];
    const float* fW    = (const float*)d_in[20];
    const float* fb    = (const float*)d_in[21];
    float* out = (float*)d_out;

    char* ws = (char*)d_ws;
    size_t off = 0;
    auto alloc = [&](size_t bytes) {
        void* p = ws + off;
        off += (bytes + 255) & ~(size_t)255;
        return p;
    };
    const int NBLK = (N_NODES + 1023) / 1024;  // 49
    int*   order  = (int*)alloc((size_t)N_EDGES * 4);
    int*   startA = (int*)alloc((size_t)(N_NODES + 1) * 4);
    int*   cursor = (int*)alloc((size_t)N_NODES * 4);
    int*   cnt    = (int*)alloc((size_t)N_NODES * 4);
    int*   incl   = (int*)alloc((size_t)NBLK * 1024 * 4);
    int*   bsum   = (int*)alloc((size_t)NBLK * 4);
    int*   bex    = (int*)alloc((size_t)NBLK * 4);
    __hip_bfloat16* h1     = (__hip_bfloat16*)alloc((size_t)N_NODES * 128 * 2);
    __hip_bfloat16* tbuf   = (__hip_bfloat16*)alloc((size_t)N_NODES * 128 * 2);
    float*          pool   = (float*)alloc((size_t)N_MOLS * 128 * 4);
    __hip_bfloat16* concat = (__hip_bfloat16*)alloc((size_t)N_NODES * 640 * 2); // 64 MB
    __hip_bfloat16* clsA   = (__hip_bfloat16*)alloc((size_t)N_NODES * 256 * 2);
    __hip_bfloat16* clsB   = (__hip_bfloat16*)alloc((size_t)N_NODES * 256 * 2);
    __hip_bfloat16* wt1    = (__hip_bfloat16*)alloc((size_t)128 * 64 * 2);
    __hip_bfloat16* wtc    = (__hip_bfloat16*)alloc((size_t)4 * 128 * 128 * 2);
    __hip_bfloat16* wtcls1 = (__hip_bfloat16*)alloc((size_t)256 * 640 * 2);
    __hip_bfloat16* wtcls  = (__hip_bfloat16*)alloc((size_t)2 * 256 * 256 * 2);

    hipMemsetAsync(cnt, 0, (size_t)N_NODES * 4, stream);
    hipMemsetAsync(pool, 0, (size_t)N_MOLS * 128 * 4, stream);

    // ---- edge sort by dst ----
    hist_kernel<<<(N_EDGES + 255) / 256, 256, 0, stream>>>(ei, cnt);
    scan1_kernel<<<NBLK, 1024, 0, stream>>>(cnt, incl, bsum);
    scan2_kernel<<<1, 64, 0, stream>>>(bsum, bex, startA, NBLK);
    scan3_kernel<<<NBLK, 1024, 0, stream>>>(cnt, incl, bex, startA, cursor);
    scatter_kernel<<<(N_EDGES + 255) / 256, 256, 0, stream>>>(ei, cursor, order);

    // ---- weight convert+transpose to bf16 [DOUT][DIN] ----
    cvt_t_kernel<<<(64 * 128 + 255) / 256, 256, 0, stream>>>(c1W, wt1, 64, 128);
    for (int i = 0; i < 4; ++i)
        cvt_t_kernel<<<(128 * 128 + 255) / 256, 256, 0, stream>>>(
            cW + (size_t)i * 128 * 128, wtc + (size_t)i * 128 * 128, 128, 128);
    cvt_t_kernel<<<(640 * 256 + 255) / 256, 256, 0, stream>>>(cls1W, wtcls1, 640, 256);
    for (int i = 0; i < 2; ++i)
        cvt_t_kernel<<<(256 * 256 + 255) / 256, 256, 0, stream>>>(
            clsW + (size_t)i * 256 * 256, wtcls + (size_t)i * 256 * 256, 256, 256);

    // ---- conv1: x [N,64] -> h1 [N,128] ----
    edge_agg_kernel<64, false><<<N_NODES, 64, 0, stream>>>(
        x, 64, ea, ei, order, startA, c1eW, c1eb, tbuf);
    mfma_lin_kernel<64, 128, 64, ACT_BN_DL><<<(N_NODES + 127) / 128, 256, 0, stream>>>(
        tbuf, 64, wt1, c1b, c1g, c1be, h1, 128);

    // ---- conv layers 0..3 -> concat slices ----
    for (int i = 0; i < 4; ++i) {
        const void* hin = (i == 0) ? (const void*)h1 : (const void*)(concat + (size_t)(i - 1) * 128);
        int ld = (i == 0) ? 128 : 640;
        edge_agg_kernel<128, true><<<N_NODES, 128, 0, stream>>>(
            hin, ld, ea, ei, order, startA,
            ceW + (size_t)i * 16 * 128, ceb + (size_t)i * 128, tbuf);
        mfma_lin_kernel<128, 128, 128, ACT_BN_DL><<<(N_NODES + 127) / 128, 256, 0, stream>>>(
            tbuf, 128, wtc + (size_t)i * 128 * 128, cb + i * 128,
            cg + i * 128, cbe + i * 128, concat + (size_t)i * 128, 640);
    }

    // ---- global add pool (cols 384..511) -> cols 512..639 ----
    pool_add_kernel<<<(N_NODES * 128 + 255) / 256, 256, 0, stream>>>(concat, batch, pool);
    pool_gather_kernel<<<(N_NODES * 128 + 255) / 256, 256, 0, stream>>>(concat, batch, pool);

    // ---- classifier ----
    mfma_lin_kernel<640, 256, 128, ACT_NONE><<<(N_NODES + 63) / 64, 256, 0, stream>>>(
        concat, 640, wtcls1, cls1b, nullptr, nullptr, clsA, 256);
    mfma_lin_kernel<256, 256, 128, ACT_LEAKY><<<(N_NODES + 63) / 64, 256, 0, stream>>>(
        clsA, 256, wtcls, clsb, nullptr, nullptr, clsB, 256);
    mfma_lin_kernel<256, 256, 128, ACT_LEAKY><<<(N_NODES + 63) / 64, 256, 0, stream>>>(
        clsB, 256, wtcls + 256 * 256, clsb + 256, nullptr, nullptr, clsA, 256);
    final_kernel<<<N_NODES / 4, 256, 0, stream>>>(clsA, fW, fb, out);
}

// Round 4
// 1221.692 us; speedup vs baseline: 1.5359x; 1.0432x over previous
//
#include <hip/hip_runtime.h>
#include <hip/hip_bf16.h>
#include <math.h>

#define N_NODES 50000
#define N_EDGES 800000
#define N_MOLS  2000
#define EPB     256   // edges per block in edge_msg_kernel (divides N_EDGES)

static constexpr float BN_INV_F = 0.9999950000374997f; // 1/sqrt(1+1e-5)

enum { ACT_NONE = 0, ACT_LEAKY = 1, ACT_BN_DL = 2 };

typedef float f32x4 __attribute__((ext_vector_type(4)));
typedef short bf16x8 __attribute__((ext_vector_type(8)));

// ---------------- counting sort of edges by dst ----------------

__global__ void hist_kernel(const int* __restrict__ ei, int* __restrict__ cnt) {
    int e = blockIdx.x * 256 + threadIdx.x;
    if (e < N_EDGES) atomicAdd(&cnt[ei[N_EDGES + e]], 1);
}

__global__ __launch_bounds__(1024) void scan1_kernel(const int* __restrict__ cnt,
                                                     int* __restrict__ incl,
                                                     int* __restrict__ bsum) {
    __shared__ int sd[1024];
    int i = blockIdx.x * 1024 + threadIdx.x;
    int v = (i < N_NODES) ? cnt[i] : 0;
    sd[threadIdx.x] = v;
    __syncthreads();
    for (int off = 1; off < 1024; off <<= 1) {
        int t = (threadIdx.x >= off) ? sd[threadIdx.x - off] : 0;
        __syncthreads();
        sd[threadIdx.x] += t;
        __syncthreads();
    }
    incl[i] = sd[threadIdx.x];
    if (threadIdx.x == 1023) bsum[blockIdx.x] = sd[1023];
}

__global__ void scan2_kernel(const int* __restrict__ bsum, int* __restrict__ bex, int nblk) {
    if (threadIdx.x == 0) {
        int run = 0;
        for (int b = 0; b < nblk; ++b) { bex[b] = run; run += bsum[b]; }
    }
}

__global__ __launch_bounds__(1024) void scan3_kernel(const int* __restrict__ cnt,
                                                     const int* __restrict__ incl,
                                                     const int* __restrict__ bex,
                                                     int* __restrict__ cursor) {
    int i = blockIdx.x * 1024 + threadIdx.x;
    if (i < N_NODES) cursor[i] = bex[blockIdx.x] + incl[i] - cnt[i];
}

// scatter: emit src/dst per sorted position AND pre-gather ea into sorted order
__global__ void scatter_kernel(const int* __restrict__ ei, int* __restrict__ cursor,
                               const float* __restrict__ ea,
                               int* __restrict__ srcs, int* __restrict__ dsts,
                               float* __restrict__ eas) {
    int e = blockIdx.x * 256 + threadIdx.x;
    if (e < N_EDGES) {
        int d = ei[N_EDGES + e];
        int pos = atomicAdd(&cursor[d], 1);
        srcs[pos] = ei[e];
        dsts[pos] = d;
        const f32x4* s4 = (const f32x4*)(ea + (size_t)e * 16);
        f32x4* d4 = (f32x4*)(eas + (size_t)pos * 16);
        d4[0] = s4[0]; d4[1] = s4[1]; d4[2] = s4[2]; d4[3] = s4[3];
    }
}

// ---------------- weight convert + transpose: W[K][Nc] f32 -> Wt[Nc][K] bf16 ----

__global__ void cvt_t_kernel(const float* __restrict__ src, __hip_bfloat16* __restrict__ dst,
                             int K, int Nc) {
    int o = blockIdx.x * 256 + threadIdx.x;
    if (o >= K * Nc) return;
    int n = o / K, k = o - n * K;
    dst[o] = __float2bfloat16(src[(size_t)k * Nc + n]);
}

// ---------------- edge-parallel segmented message aggregation ----------------
// t32[v][f] += sum_{e: dst=v} relu(hin[src_e][f] + (ea_e @ eW + eb)[f])
// Block owns EPB consecutive dst-sorted edges; all D threads walk the same
// edge sequence (f = threadIdx.x); run-flush via f32 atomicAdd on dst change.

template<int D, bool F32IN>
__global__ __launch_bounds__(D) void edge_msg_kernel(
        const void* __restrict__ hin_, int ld,
        const float* __restrict__ eas,   // [E,16] dst-sorted
        const int* __restrict__ srcs,    // [E]
        const int* __restrict__ dsts,    // [E]
        const float* __restrict__ eW,    // [16, D]
        const float* __restrict__ eb,    // [D]
        float* __restrict__ t32) {
    const float* hf = (const float*)hin_;
    const __hip_bfloat16* hb = (const __hip_bfloat16*)hin_;
    const int f = threadIdx.x;
    float w[16];
#pragma unroll
    for (int k = 0; k < 16; ++k) w[k] = eW[k * D + f];
    const float ebf = eb[f];
    const int p0 = blockIdx.x * EPB;
    int cur = dsts[p0];
    float acc = 0.f;
    for (int p = p0; p < p0 + EPB; p += 4) {
        int s[4], d[4];
#pragma unroll
        for (int j = 0; j < 4; ++j) { s[j] = srcs[p + j]; d[j] = dsts[p + j]; }
        float h[4];
#pragma unroll
        for (int j = 0; j < 4; ++j)
            h[j] = F32IN ? hf[(size_t)s[j] * ld + f]
                         : __bfloat162float(hb[(size_t)s[j] * ld + f]);
        float ev[4];
#pragma unroll
        for (int j = 0; j < 4; ++j) {
            const f32x4* ap = (const f32x4*)(eas + (size_t)(p + j) * 16);
            f32x4 a0 = ap[0], a1 = ap[1], a2 = ap[2], a3 = ap[3];
            float e0 = ebf;
            e0 += a0.x * w[0]  + a0.y * w[1]  + a0.z * w[2]  + a0.w * w[3];
            e0 += a1.x * w[4]  + a1.y * w[5]  + a1.z * w[6]  + a1.w * w[7];
            e0 += a2.x * w[8]  + a2.y * w[9]  + a2.z * w[10] + a2.w * w[11];
            e0 += a3.x * w[12] + a3.y * w[13] + a3.z * w[14] + a3.w * w[15];
            ev[j] = e0;
        }
#pragma unroll
        for (int j = 0; j < 4; ++j) {
            if (d[j] != cur) {              // wave-uniform branch
                atomicAdd(&t32[(size_t)cur * D + f], acc);
                acc = 0.f; cur = d[j];
            }
            acc += fmaxf(h[j] + ev[j], 0.f);
        }
    }
    atomicAdd(&t32[(size_t)cur * D + f], acc);
}

// fuse self term + convert to bf16 for MFMA A: tb[v][f] = bf16(hin[v][f] + t32[v][f])
template<int D, bool F32IN>
__global__ void fuse_kernel(const void* __restrict__ hin_, int ld,
                            const float* __restrict__ t32,
                            __hip_bfloat16* __restrict__ tb) {
    int idx = blockIdx.x * 256 + threadIdx.x;
    if (idx >= N_NODES * D) return;
    int n = idx / D, f = idx - n * D;
    float hv = F32IN ? ((const float*)hin_)[(size_t)n * ld + f]
                     : __bfloat162float(((const __hip_bfloat16*)hin_)[(size_t)n * ld + f]);
    tb[idx] = __float2bfloat16(hv + t32[idx]);
}

// ---------------- bf16 MFMA linear: C = act(A @ W + b) ----------------

template<int DIN, int DOUT, int KCHUNK, int ACT>
__global__ __launch_bounds__(256) void mfma_lin_kernel(
        const __hip_bfloat16* __restrict__ A, int lda,
        const __hip_bfloat16* __restrict__ Wt,  // [DOUT][DIN]
        const float* __restrict__ bias,
        const float* __restrict__ gamma,
        const float* __restrict__ beta,
        __hip_bfloat16* __restrict__ C, int ldc) {
    constexpr int WCOLS = DOUT / 64;
    constexpr int WROWS = 4 / WCOLS;
    constexpr int BROWS = WROWS * 64;
    constexpr int NKS = KCHUNK / 32;
    constexpr int NCH = DIN / KCHUNK;
    const int wid = threadIdx.x >> 6, lane = threadIdx.x & 63;
    const int wr = wid / WCOLS, wc = wid % WCOLS;
    const int row_base = blockIdx.x * BROWS + wr * 64;
    const int col0 = wc * 64;
    const int lrow = lane & 15;
    const int lk = (lane >> 4) * 8;

    f32x4 acc[4][4];
#pragma unroll
    for (int i = 0; i < 4; ++i)
#pragma unroll
        for (int j = 0; j < 4; ++j) acc[i][j] = (f32x4){0.f, 0.f, 0.f, 0.f};

    for (int ch = 0; ch < NCH; ++ch) {
        const int kc = ch * KCHUNK;
        bf16x8 b[4][NKS];
#pragma unroll
        for (int ct = 0; ct < 4; ++ct)
#pragma unroll
            for (int ks = 0; ks < NKS; ++ks)
                b[ct][ks] = *reinterpret_cast<const bf16x8*>(
                    &Wt[(size_t)(col0 + ct * 16 + lrow) * DIN + kc + ks * 32 + lk]);
#pragma unroll
        for (int rt = 0; rt < 4; ++rt) {
            int arow = row_base + rt * 16 + lrow;
            arow = arow < N_NODES ? arow : N_NODES - 1;
            bf16x8 a[NKS];
#pragma unroll
            for (int ks = 0; ks < NKS; ++ks)
                a[ks] = *reinterpret_cast<const bf16x8*>(
                    &A[(size_t)arow * lda + kc + ks * 32 + lk]);
#pragma unroll
            for (int ct = 0; ct < 4; ++ct)
#pragma unroll
                for (int ks = 0; ks < NKS; ++ks)
                    acc[rt][ct] = __builtin_amdgcn_mfma_f32_16x16x32_bf16(
                        a[ks], b[ct][ks], acc[rt][ct], 0, 0, 0);
        }
    }

#pragma unroll
    for (int rt = 0; rt < 4; ++rt) {
        int r0 = row_base + rt * 16 + (lane >> 4) * 4;
#pragma unroll
        for (int ct = 0; ct < 4; ++ct) {
            int c = col0 + ct * 16 + lrow;
            float bi = bias[c];
            float ga = (ACT == ACT_BN_DL) ? gamma[c] : 0.f;
            float be = (ACT == ACT_BN_DL) ? beta[c] : 0.f;
#pragma unroll
            for (int r = 0; r < 4; ++r) {
                int row = r0 + r;
                if (row < N_NODES) {
                    float v = acc[rt][ct][r] + bi;
                    if (ACT == ACT_BN_DL) {
                        v = ga * (v * BN_INV_F) + be;
                        v = v > 0.f ? v : 1e-4f * v;   // leaky(leaky(v))
                    } else if (ACT == ACT_LEAKY) {
                        v = v > 0.f ? v : 0.01f * v;
                    }
                    C[(size_t)row * ldc + c] = __float2bfloat16(v);
                }
            }
        }
    }
}

// ---------------- pooling ----------------

__global__ void pool_add_kernel(const __hip_bfloat16* __restrict__ concat,
                                const int* __restrict__ batch,
                                float* __restrict__ pool) {
    int idx = blockIdx.x * 256 + threadIdx.x;
    if (idx >= N_NODES * 128) return;
    int n = idx >> 7, f = idx & 127;
    atomicAdd(&pool[batch[n] * 128 + f],
              __bfloat162float(concat[(size_t)n * 640 + 384 + f]));
}

__global__ void pool_gather_kernel(__hip_bfloat16* __restrict__ concat,
                                   const int* __restrict__ batch,
                                   const float* __restrict__ pool) {
    int idx = blockIdx.x * 256 + threadIdx.x;
    if (idx >= N_NODES * 128) return;
    int n = idx >> 7, f = idx & 127;
    concat[(size_t)n * 640 + 512 + f] = __float2bfloat16(pool[batch[n] * 128 + f]);
}

// ---------------- final 256 -> 1 + sigmoid ----------------

__global__ __launch_bounds__(256) void final_kernel(const __hip_bfloat16* __restrict__ A,
                                                    const float* __restrict__ fW,
                                                    const float* __restrict__ fb,
                                                    float* __restrict__ out) {
    int wave = threadIdx.x >> 6;
    int lane = threadIdx.x & 63;
    int row = blockIdx.x * 4 + wave;
    const __hip_bfloat16* ar = A + (size_t)row * 256;
    float p = 0.f;
#pragma unroll
    for (int i = 0; i < 4; ++i) {
        int k = lane + i * 64;
        p += __bfloat162float(ar[k]) * fW[k];
    }
#pragma unroll
    for (int off = 32; off >= 1; off >>= 1) p += __shfl_xor(p, off, 64);
    if (lane == 0) out[row] = 1.f / (1.f + expf(-(p + fb[0])));
}

// ---------------- launch ----------------

extern "C" void kernel_launch(void* const* d_in, const int* in_sizes, int n_in,
                              void* d_out, int out_size, void* d_ws, size_t ws_size,
                              hipStream_t stream) {
    const float* x     = (const float*)d_in[0];
    const int*   ei    = (const int*)d_in[1];
    const float* ea    = (const float*)d_in[2];
    const int*   batch = (const int*)d_in[3];
    const float* c1W   = (const float*)d_in[4];
    const float* c1b   = (const float*)d_in[5];
    const float* c1g   = (const float*)d_in[6];
    const float* c1be  = (const float*)d_in[7];
    const float* c1eW  = (const float*)d_in[8];
    const float* c1eb  = (const float*)d_in[9];
    const float* cW    = (const float*)d_in[10];
    const float* cb    = (const float*)d_in[11];
    const float* cg    = (const float*)d_in[12];
    const float* cbe   = (const float*)d_in[13];
    const float* ceW   = (const float*)d_in[14];
    const float* ceb   = (const float*)d_in[15];
    const float* cls1W = (const float*)d_in[16];
    const float* cls1b = (const float*)d_in[17];
    const float* clsW  = (const float*)d_in[18];
    const float* clsb  = (const float*)d_in[19];
    const float* fW    = (const float*)d_in[20];
    const float* fb    = (const float*)d_in[21];
    float* out = (float*)d_out;

    char* ws = (char*)d_ws;
    size_t off = 0;
    auto alloc = [&](size_t bytes) {
        void* p = ws + off;
        off += (bytes + 255) & ~(size_t)255;
        return p;
    };
    const int NBLK = (N_NODES + 1023) / 1024;  // 49
    int*   srcs   = (int*)alloc((size_t)N_EDGES * 4);
    int*   dsts   = (int*)alloc((size_t)N_EDGES * 4);
    int*   cursor = (int*)alloc((size_t)N_NODES * 4);
    int*   cnt    = (int*)alloc((size_t)N_NODES * 4);
    int*   incl   = (int*)alloc((size_t)NBLK * 1024 * 4);
    int*   bsum   = (int*)alloc((size_t)NBLK * 4);
    int*   bex    = (int*)alloc((size_t)NBLK * 4);
    float* eas    = (float*)alloc((size_t)N_EDGES * 16 * 4);       // 51.2 MB
    float* t32    = (float*)alloc((size_t)N_NODES * 128 * 4);      // 25.6 MB
    __hip_bfloat16* h1     = (__hip_bfloat16*)alloc((size_t)N_NODES * 128 * 2);
    __hip_bfloat16* tbuf   = (__hip_bfloat16*)alloc((size_t)N_NODES * 128 * 2);
    float*          pool   = (float*)alloc((size_t)N_MOLS * 128 * 4);
    __hip_bfloat16* concat = (__hip_bfloat16*)alloc((size_t)N_NODES * 640 * 2); // 64 MB
    __hip_bfloat16* clsA   = (__hip_bfloat16*)alloc((size_t)N_NODES * 256 * 2);
    __hip_bfloat16* wt1    = (__hip_bfloat16*)alloc((size_t)128 * 64 * 2);
    __hip_bfloat16* wtc    = (__hip_bfloat16*)alloc((size_t)4 * 128 * 128 * 2);
    __hip_bfloat16* wtcls1 = (__hip_bfloat16*)alloc((size_t)256 * 640 * 2);
    __hip_bfloat16* wtcls  = (__hip_bfloat16*)alloc((size_t)2 * 256 * 256 * 2);
    __hip_bfloat16* clsB   = concat;  // overlay: concat dead after cls1

    hipMemsetAsync(cnt, 0, (size_t)N_NODES * 4, stream);
    hipMemsetAsync(pool, 0, (size_t)N_MOLS * 128 * 4, stream);

    // ---- edge sort by dst (emits srcs/dsts/ea_sorted) ----
    hist_kernel<<<(N_EDGES + 255) / 256, 256, 0, stream>>>(ei, cnt);
    scan1_kernel<<<NBLK, 1024, 0, stream>>>(cnt, incl, bsum);
    scan2_kernel<<<1, 64, 0, stream>>>(bsum, bex, NBLK);
    scan3_kernel<<<NBLK, 1024, 0, stream>>>(cnt, incl, bex, cursor);
    scatter_kernel<<<(N_EDGES + 255) / 256, 256, 0, stream>>>(ei, cursor, ea, srcs, dsts, eas);

    // ---- weight convert+transpose to bf16 [DOUT][DIN] ----
    cvt_t_kernel<<<(64 * 128 + 255) / 256, 256, 0, stream>>>(c1W, wt1, 64, 128);
    for (int i = 0; i < 4; ++i)
        cvt_t_kernel<<<(128 * 128 + 255) / 256, 256, 0, stream>>>(
            cW + (size_t)i * 128 * 128, wtc + (size_t)i * 128 * 128, 128, 128);
    cvt_t_kernel<<<(640 * 256 + 255) / 256, 256, 0, stream>>>(cls1W, wtcls1, 640, 256);
    for (int i = 0; i < 2; ++i)
        cvt_t_kernel<<<(256 * 256 + 255) / 256, 256, 0, stream>>>(
            clsW + (size_t)i * 256 * 256, wtcls + (size_t)i * 256 * 256, 256, 256);

    const int NEB = N_EDGES / EPB;  // 3125

    // ---- conv1: x [N,64] f32 -> h1 [N,128] ----
    hipMemsetAsync(t32, 0, (size_t)N_NODES * 64 * 4, stream);
    edge_msg_kernel<64, true><<<NEB, 64, 0, stream>>>(
        x, 64, eas, srcs, dsts, c1eW, c1eb, t32);
    fuse_kernel<64, true><<<(N_NODES * 64 + 255) / 256, 256, 0, stream>>>(x, 64, t32, tbuf);
    mfma_lin_kernel<64, 128, 64, ACT_BN_DL><<<(N_NODES + 127) / 128, 256, 0, stream>>>(
        tbuf, 64, wt1, c1b, c1g, c1be, h1, 128);

    // ---- conv layers 0..3 -> concat slices ----
    for (int i = 0; i < 4; ++i) {
        const void* hin = (i == 0) ? (const void*)h1 : (const void*)(concat + (size_t)(i - 1) * 128);
        int ld = (i == 0) ? 128 : 640;
        hipMemsetAsync(t32, 0, (size_t)N_NODES * 128 * 4, stream);
        edge_msg_kernel<128, false><<<NEB, 128, 0, stream>>>(
            hin, ld, eas, srcs, dsts, ceW + (size_t)i * 16 * 128, ceb + (size_t)i * 128, t32);
        fuse_kernel<128, false><<<(N_NODES * 128 + 255) / 256, 256, 0, stream>>>(
            hin, ld, t32, tbuf);
        mfma_lin_kernel<128, 128, 128, ACT_BN_DL><<<(N_NODES + 127) / 128, 256, 0, stream>>>(
            tbuf, 128, wtc + (size_t)i * 128 * 128, cb + i * 128,
            cg + i * 128, cbe + i * 128, concat + (size_t)i * 128, 640);
    }

    // ---- global add pool (cols 384..511) -> cols 512..639 ----
    pool_add_kernel<<<(N_NODES * 128 + 255) / 256, 256, 0, stream>>>(concat, batch, pool);
    pool_gather_kernel<<<(N_NODES * 128 + 255) / 256, 256, 0, stream>>>(concat, batch, pool);

    // ---- classifier ----
    mfma_lin_kernel<640, 256, 128, ACT_NONE><<<(N_NODES + 63) / 64, 256, 0, stream>>>(
        concat, 640, wtcls1, cls1b, nullptr, nullptr, clsA, 256);
    mfma_lin_kernel<256, 256, 128, ACT_LEAKY><<<(N_NODES + 63) / 64, 256, 0, stream>>>(
        clsA, 256, wtcls, clsb, nullptr, nullptr, clsB, 256);
    mfma_lin_kernel<256, 256, 128, ACT_LEAKY><<<(N_NODES + 63) / 64, 256, 0, stream>>>(
        clsB, 256, wtcls + 256 * 256, clsb + 256, nullptr, nullptr, clsA, 256);
    final_kernel<<<N_NODES / 4, 256, 0, stream>>>(clsA, fW, fb, out);
}

// Round 6
// 934.675 us; speedup vs baseline: 2.0076x; 1.3071x over previous
//
#include <hip/hip_runtime.h>
#include <hip/hip_bf16.h>
#include <math.h>

#define N_NODES 50000
#define N_EDGES 800000
#define N_MOLS  2000
#define EPB     128   // edges per block in edge_mfma_kernel (divides N_EDGES)

static constexpr float BN_INV_F = 0.9999950000374997f; // 1/sqrt(1+1e-5)

enum { ACT_NONE = 0, ACT_LEAKY = 1, ACT_BN_DL = 2 };

typedef float f32x4 __attribute__((ext_vector_type(4)));
typedef short bf16x8 __attribute__((ext_vector_type(8)));

static __device__ __forceinline__ float b2f(short s) {
    unsigned u = ((unsigned)(unsigned short)s) << 16;
    return __builtin_bit_cast(float, u);
}
static __device__ __forceinline__ short f2bs(float v) {
    return __builtin_bit_cast(short, __float2bfloat16(v));
}

// ---------------- counting sort of edges by dst ----------------

__global__ void hist_kernel(const int* __restrict__ ei, int* __restrict__ cnt) {
    int e = blockIdx.x * 256 + threadIdx.x;
    if (e < N_EDGES) atomicAdd(&cnt[ei[N_EDGES + e]], 1);
}

__global__ __launch_bounds__(1024) void scan1_kernel(const int* __restrict__ cnt,
                                                     int* __restrict__ incl,
                                                     int* __restrict__ bsum) {
    __shared__ int sd[1024];
    int i = blockIdx.x * 1024 + threadIdx.x;
    int v = (i < N_NODES) ? cnt[i] : 0;
    sd[threadIdx.x] = v;
    __syncthreads();
    for (int off = 1; off < 1024; off <<= 1) {
        int t = (threadIdx.x >= off) ? sd[threadIdx.x - off] : 0;
        __syncthreads();
        sd[threadIdx.x] += t;
        __syncthreads();
    }
    incl[i] = sd[threadIdx.x];
    if (threadIdx.x == 1023) bsum[blockIdx.x] = sd[1023];
}

__global__ void scan2_kernel(const int* __restrict__ bsum, int* __restrict__ bex, int nblk) {
    if (threadIdx.x == 0) {
        int run = 0;
        for (int b = 0; b < nblk; ++b) { bex[b] = run; run += bsum[b]; }
    }
}

__global__ __launch_bounds__(1024) void scan3_kernel(const int* __restrict__ cnt,
                                                     const int* __restrict__ incl,
                                                     const int* __restrict__ bex,
                                                     int* __restrict__ cursor) {
    int i = blockIdx.x * 1024 + threadIdx.x;
    if (i < N_NODES) cursor[i] = bex[blockIdx.x] + incl[i] - cnt[i];
}

// scatter: emit src/dst per sorted position AND pre-gather ea (as bf16) into sorted order
__global__ void scatter_kernel(const int* __restrict__ ei, int* __restrict__ cursor,
                               const float* __restrict__ ea,
                               int* __restrict__ srcs, int* __restrict__ dsts,
                               __hip_bfloat16* __restrict__ eas) {
    int e = blockIdx.x * 256 + threadIdx.x;
    if (e < N_EDGES) {
        int d = ei[N_EDGES + e];
        int pos = atomicAdd(&cursor[d], 1);
        srcs[pos] = ei[e];
        dsts[pos] = d;
        const f32x4* s4 = (const f32x4*)(ea + (size_t)e * 16);
        f32x4 a0 = s4[0], a1 = s4[1], a2 = s4[2], a3 = s4[3];
        bf16x8 lo, hi;
#pragma unroll
        for (int j = 0; j < 4; ++j) {
            lo[j] = f2bs(a0[j]); lo[4 + j] = f2bs(a1[j]);
            hi[j] = f2bs(a2[j]); hi[4 + j] = f2bs(a3[j]);
        }
        bf16x8* d8 = (bf16x8*)(eas + (size_t)pos * 16);
        d8[0] = lo; d8[1] = hi;
    }
}

// ---------------- all weight converts/transposes in one launch ----------------
// Wt layouts: [DOUT][DIN] bf16 for node/cls weights; [D][16] bf16 for edge weights.

__global__ __launch_bounds__(256) void cvt_all_kernel(
        const float* __restrict__ c1W, const float* __restrict__ cW,
        const float* __restrict__ cls1W, const float* __restrict__ clsW,
        const float* __restrict__ c1eW, const float* __restrict__ ceW,
        __hip_bfloat16* __restrict__ wt1, __hip_bfloat16* __restrict__ wtc,
        __hip_bfloat16* __restrict__ wtcls1, __hip_bfloat16* __restrict__ wtcls,
        __hip_bfloat16* __restrict__ ewt1, __hip_bfloat16* __restrict__ ewtc) {
    int o = blockIdx.x * 256 + threadIdx.x;
    auto cvt = [](const float* s, __hip_bfloat16* d, int K, int Nc, int off) {
        int n = off / K, k = off - n * K;
        d[off] = __float2bfloat16(s[(size_t)k * Nc + n]);
    };
    if (o < 8192) cvt(c1W, wt1, 64, 128, o);
    else if (o < 73728)  { int s = o - 8192;   int i = s >> 14, off = s & 16383;
        cvt(cW + i * 16384, wtc + i * 16384, 128, 128, off); }
    else if (o < 237568) cvt(cls1W, wtcls1, 640, 256, o - 73728);
    else if (o < 368640) { int s = o - 237568; int i = s >> 16, off = s & 65535;
        cvt(clsW + i * 65536, wtcls + i * 65536, 256, 256, off); }
    else if (o < 369664) cvt(c1eW, ewt1, 16, 64, o - 368640);
    else if (o < 377856) { int s = o - 369664; int i = s >> 11, off = s & 2047;
        cvt(ceW + i * 2048, ewtc + i * 2048, 16, 128, off); }
}

// ---------------- edge kernel: MFMA e-linear + segmented aggregation ----------------
// phase A: e[128][D] = eas_block[128][16] @ eWt^T + eb  (MFMA, K=16 zero-padded to 32) -> LDS bf16
// phase B: GROUPS feature-wide groups each walk EPB/GROUPS dst-sorted edges,
//          acc += relu(h[src][f] + e), run-flush via f32 atomicAdd on dst change.

template<int D, bool F32IN>
__global__ __launch_bounds__(256) void edge_mfma_kernel(
        const void* __restrict__ hin_, int ld,
        const __hip_bfloat16* __restrict__ eas,   // [E][16] bf16, dst-sorted
        const int* __restrict__ srcs,
        const int* __restrict__ dsts,
        const __hip_bfloat16* __restrict__ eWt,   // [D][16] bf16
        const float* __restrict__ eb,             // [D]
        float* __restrict__ t32) {
    constexpr int SP = D + 4;          // LDS row stride (bf16 elems)
    constexpr int NCT = D / 16;        // col tiles
    constexpr int GROUPS = 256 / D;
    constexpr int EPG = EPB / GROUPS;
    __shared__ __hip_bfloat16 e_lds[EPB * SP];
    const int tid = threadIdx.x;
    const int wid = tid >> 6, lane = tid & 63;
    const int lrow = lane & 15;
    const int lkg = lane >> 4;         // 0..3
    const bool hiK = lkg >= 2;         // k 16..31 -> zero pad
    const int lko = (lkg & 1) * 8;     // offset within the 16 real k's
    const int p0 = blockIdx.x * EPB;

    // ---- phase A ----
    bf16x8 bfrag[NCT];
#pragma unroll
    for (int ct = 0; ct < NCT; ++ct) {
        bf16x8 bv = *reinterpret_cast<const bf16x8*>(&eWt[(ct * 16 + lrow) * 16 + lko]);
        if (hiK) bv = (bf16x8){0, 0, 0, 0, 0, 0, 0, 0};
        bfrag[ct] = bv;
    }
#pragma unroll
    for (int et = 0; et < 2; ++et) {
        const int erow = (wid * 2 + et) * 16;   // local edge tile base
        bf16x8 av = *reinterpret_cast<const bf16x8*>(
            &eas[(size_t)(p0 + erow + lrow) * 16 + lko]);
        if (hiK) av = (bf16x8){0, 0, 0, 0, 0, 0, 0, 0};
        const int r0 = erow + lkg * 4;
#pragma unroll
        for (int ct = 0; ct < NCT; ++ct) {
            f32x4 c = (f32x4){0.f, 0.f, 0.f, 0.f};
            c = __builtin_amdgcn_mfma_f32_16x16x32_bf16(av, bfrag[ct], c, 0, 0, 0);
            const int col = ct * 16 + lrow;
            const float bi = eb[col];
#pragma unroll
            for (int r = 0; r < 4; ++r)
                e_lds[(r0 + r) * SP + col] = __float2bfloat16(c[r] + bi);
        }
    }
    __syncthreads();

    // ---- phase B ----
    const float* hf = (const float*)hin_;
    const __hip_bfloat16* hb = (const __hip_bfloat16*)hin_;
    const int g = tid / D;
    const int f = tid - g * D;
    const int q0 = g * EPG;
    int cur = dsts[p0 + q0];
    float acc = 0.f;
    for (int q = q0; q < q0 + EPG; q += 8) {
        int s[8], d[8];
#pragma unroll
        for (int j = 0; j < 8; ++j) { s[j] = srcs[p0 + q + j]; d[j] = dsts[p0 + q + j]; }
        float h[8];
#pragma unroll
        for (int j = 0; j < 8; ++j)
            h[j] = F32IN ? hf[(size_t)s[j] * ld + f]
                         : __bfloat162float(hb[(size_t)s[j] * ld + f]);
        float e[8];
#pragma unroll
        for (int j = 0; j < 8; ++j)
            e[j] = __bfloat162float(e_lds[(q + j) * SP + f]);
#pragma unroll
        for (int j = 0; j < 8; ++j) {
            if (d[j] != cur) {             // group-uniform branch
                atomicAdd(&t32[(size_t)cur * D + f], acc);
                acc = 0.f; cur = d[j];
            }
            acc += fmaxf(h[j] + e[j], 0.f);
        }
    }
    atomicAdd(&t32[(size_t)cur * D + f], acc);
}

// ---------------- bf16 MFMA linear: C = act((t32 + hin) @ W + b) ----------------
// SELF: 0 = plain bf16 A (A_ = bf16 matrix); 1 = t32 + f32 hin; 2 = t32 + bf16 hin.
// 4 waves = WR x WC; each wave MT x NT tiles of 16x16. BROWS = WR*MT*16.

template<int DIN, int DOUT, int WR, int WC, int MT, int NT, int ACT, int SELF>
__global__ __launch_bounds__(256) void mfma_lin_kernel(
        const void* __restrict__ A_, int lda,
        const float* __restrict__ t32,
        const __hip_bfloat16* __restrict__ Wt,  // [DOUT][DIN]
        const float* __restrict__ bias,
        const float* __restrict__ gamma,
        const float* __restrict__ beta,
        __hip_bfloat16* __restrict__ C, int ldc) {
    constexpr int BROWS = WR * MT * 16;
    constexpr int NKS = DIN / 32;
    static_assert(WC * NT * 16 == DOUT, "cols");
    static_assert(WR * WC == 4, "waves");
    const int wid = threadIdx.x >> 6, lane = threadIdx.x & 63;
    const int wr = wid / WC, wc = wid % WC;
    const int row_base = blockIdx.x * BROWS + wr * MT * 16;
    const int col0 = wc * NT * 16;
    const int lrow = lane & 15;
    const int lk = (lane >> 4) * 8;

    f32x4 acc[MT][NT];
#pragma unroll
    for (int i = 0; i < MT; ++i)
#pragma unroll
        for (int j = 0; j < NT; ++j) acc[i][j] = (f32x4){0.f, 0.f, 0.f, 0.f};

    for (int ks = 0; ks < NKS; ++ks) {
        const int kc = ks * 32 + lk;
        bf16x8 b[NT];
#pragma unroll
        for (int nt = 0; nt < NT; ++nt)
            b[nt] = *reinterpret_cast<const bf16x8*>(
                &Wt[(size_t)(col0 + nt * 16 + lrow) * DIN + kc]);
#pragma unroll
        for (int mt = 0; mt < MT; ++mt) {
            int arow = row_base + mt * 16 + lrow;
            arow = arow < N_NODES ? arow : N_NODES - 1;
            bf16x8 a;
            if constexpr (SELF == 0) {
                a = *reinterpret_cast<const bf16x8*>(
                    &((const __hip_bfloat16*)A_)[(size_t)arow * lda + kc]);
            } else {
                f32x4 t0 = *(const f32x4*)&t32[(size_t)arow * DIN + kc];
                f32x4 t1 = *(const f32x4*)&t32[(size_t)arow * DIN + kc + 4];
                if constexpr (SELF == 1) {
                    f32x4 h0 = *(const f32x4*)&((const float*)A_)[(size_t)arow * lda + kc];
                    f32x4 h1 = *(const f32x4*)&((const float*)A_)[(size_t)arow * lda + kc + 4];
#pragma unroll
                    for (int j = 0; j < 4; ++j) {
                        a[j]     = f2bs(t0[j] + h0[j]);
                        a[4 + j] = f2bs(t1[j] + h1[j]);
                    }
                } else {
                    bf16x8 hv = *reinterpret_cast<const bf16x8*>(
                        &((const __hip_bfloat16*)A_)[(size_t)arow * lda + kc]);
#pragma unroll
                    for (int j = 0; j < 4; ++j) {
                        a[j]     = f2bs(t0[j] + b2f(hv[j]));
                        a[4 + j] = f2bs(t1[j] + b2f(hv[4 + j]));
                    }
                }
            }
#pragma unroll
            for (int nt = 0; nt < NT; ++nt)
                acc[mt][nt] = __builtin_amdgcn_mfma_f32_16x16x32_bf16(
                    a, b[nt], acc[mt][nt], 0, 0, 0);
        }
    }

#pragma unroll
    for (int mt = 0; mt < MT; ++mt) {
        int r0 = row_base + mt * 16 + (lane >> 4) * 4;
#pragma unroll
        for (int nt = 0; nt < NT; ++nt) {
            int c = col0 + nt * 16 + lrow;
            float bi = bias[c];
            float ga = (ACT == ACT_BN_DL) ? gamma[c] : 0.f;
            float be = (ACT == ACT_BN_DL) ? beta[c] : 0.f;
#pragma unroll
            for (int r = 0; r < 4; ++r) {
                int row = r0 + r;
                if (row < N_NODES) {
                    float v = acc[mt][nt][r] + bi;
                    if (ACT == ACT_BN_DL) {
                        v = ga * (v * BN_INV_F) + be;
                        v = v > 0.f ? v : 1e-4f * v;   // leaky(leaky(v))
                    } else if (ACT == ACT_LEAKY) {
                        v = v > 0.f ? v : 0.01f * v;
                    }
                    C[(size_t)row * ldc + c] = __float2bfloat16(v);
                }
            }
        }
    }
}

// ---------------- pooling ----------------

__global__ void pool_add_kernel(const __hip_bfloat16* __restrict__ concat,
                                const int* __restrict__ batch,
                                float* __restrict__ pool) {
    int idx = blockIdx.x * 256 + threadIdx.x;
    if (idx >= N_NODES * 128) return;
    int n = idx >> 7, f = idx & 127;
    atomicAdd(&pool[batch[n] * 128 + f],
              __bfloat162float(concat[(size_t)n * 640 + 384 + f]));
}

__global__ void pool_gather_kernel(__hip_bfloat16* __restrict__ concat,
                                   const int* __restrict__ batch,
                                   const float* __restrict__ pool) {
    int idx = blockIdx.x * 256 + threadIdx.x;
    if (idx >= N_NODES * 128) return;
    int n = idx >> 7, f = idx & 127;
    concat[(size_t)n * 640 + 512 + f] = __float2bfloat16(pool[batch[n] * 128 + f]);
}

// ---------------- final 256 -> 1 + sigmoid ----------------

__global__ __launch_bounds__(256) void final_kernel(const __hip_bfloat16* __restrict__ A,
                                                    const float* __restrict__ fW,
                                                    const float* __restrict__ fb,
                                                    float* __restrict__ out) {
    int wave = threadIdx.x >> 6;
    int lane = threadIdx.x & 63;
    int row = blockIdx.x * 4 + wave;
    const __hip_bfloat16* ar = A + (size_t)row * 256;
    float p = 0.f;
#pragma unroll
    for (int i = 0; i < 4; ++i) {
        int k = lane + i * 64;
        p += __bfloat162float(ar[k]) * fW[k];
    }
#pragma unroll
    for (int off = 32; off >= 1; off >>= 1) p += __shfl_xor(p, off, 64);
    if (lane == 0) out[row] = 1.f / (1.f + expf(-(p + fb[0])));
}

// ---------------- launch ----------------

extern "C" void kernel_launch(void* const* d_in, const int* in_sizes, int n_in,
                              void* d_out, int out_size, void* d_ws, size_t ws_size,
                              hipStream_t stream) {
    const float* x     = (const float*)d_in[0];
    const int*   ei    = (const int*)d_in[1];
    const float* ea    = (const float*)d_in[2];
    const int*   batch = (const int*)d_in[3];
    const float* c1W   = (const float*)d_in[4];
    const float* c1b   = (const float*)d_in[5];
    const float* c1g   = (const float*)d_in[6];
    const float* c1be  = (const float*)d_in[7];
    const float* c1eW  = (const float*)d_in[8];
    const float* c1eb  = (const float*)d_in[9];
    const float* cW    = (const float*)d_in[10];
    const float* cb    = (const float*)d_in[11];
    const float* cg    = (const float*)d_in[12];
    const float* cbe   = (const float*)d_in[13];
    const float* ceW   = (const float*)d_in[14];
    const float* ceb   = (const float*)d_in[15];
    const float* cls1W = (const float*)d_in[16];
    const float* cls1b = (const float*)d_in[17];
    const float* clsW  = (const float*)d_in[18];
    const float* clsb  = (const float*)d_in[19];
    const float* fW    = (const float*)d_in[20];
    const float* fb    = (const float*)d_in[21];
    float* out = (float*)d_out;

    char* ws = (char*)d_ws;
    size_t off = 0;
    auto alloc = [&](size_t bytes) {
        void* p = ws + off;
        off += (bytes + 255) & ~(size_t)255;
        return p;
    };
    const int NBLK = (N_NODES + 1023) / 1024;  // 49
    int*   srcs   = (int*)alloc((size_t)N_EDGES * 4);
    int*   dsts   = (int*)alloc((size_t)N_EDGES * 4);
    int*   cursor = (int*)alloc((size_t)N_NODES * 4);
    int*   cnt    = (int*)alloc((size_t)N_NODES * 4);
    int*   incl   = (int*)alloc((size_t)NBLK * 1024 * 4);
    int*   bsum   = (int*)alloc((size_t)NBLK * 4);
    int*   bex    = (int*)alloc((size_t)NBLK * 4);
    __hip_bfloat16* eas = (__hip_bfloat16*)alloc((size_t)N_EDGES * 16 * 2);  // 25.6 MB
    float* t32    = (float*)alloc((size_t)N_NODES * 128 * 4);                // 25.6 MB
    __hip_bfloat16* h1     = (__hip_bfloat16*)alloc((size_t)N_NODES * 128 * 2);
    float*          pool   = (float*)alloc((size_t)N_MOLS * 128 * 4);
    __hip_bfloat16* concat = (__hip_bfloat16*)alloc((size_t)N_NODES * 640 * 2); // 64 MB
    __hip_bfloat16* clsA   = (__hip_bfloat16*)alloc((size_t)N_NODES * 256 * 2);
    __hip_bfloat16* wt1    = (__hip_bfloat16*)alloc((size_t)128 * 64 * 2);
    __hip_bfloat16* wtc    = (__hip_bfloat16*)alloc((size_t)4 * 128 * 128 * 2);
    __hip_bfloat16* wtcls1 = (__hip_bfloat16*)alloc((size_t)256 * 640 * 2);
    __hip_bfloat16* wtcls  = (__hip_bfloat16*)alloc((size_t)2 * 256 * 256 * 2);
    __hip_bfloat16* ewt1   = (__hip_bfloat16*)alloc((size_t)64 * 16 * 2);
    __hip_bfloat16* ewtc   = (__hip_bfloat16*)alloc((size_t)4 * 128 * 16 * 2);
    __hip_bfloat16* clsB   = concat;  // overlay: concat dead after cls1

    hipMemsetAsync(cnt, 0, (size_t)N_NODES * 4, stream);
    hipMemsetAsync(pool, 0, (size_t)N_MOLS * 128 * 4, stream);

    // ---- edge sort by dst (emits srcs/dsts/eas-bf16) ----
    hist_kernel<<<(N_EDGES + 255) / 256, 256, 0, stream>>>(ei, cnt);
    scan1_kernel<<<NBLK, 1024, 0, stream>>>(cnt, incl, bsum);
    scan2_kernel<<<1, 64, 0, stream>>>(bsum, bex, NBLK);
    scan3_kernel<<<NBLK, 1024, 0, stream>>>(cnt, incl, bex, cursor);
    scatter_kernel<<<(N_EDGES + 255) / 256, 256, 0, stream>>>(ei, cursor, ea, srcs, dsts, eas);

    // ---- all weight converts in one launch ----
    cvt_all_kernel<<<(377856 + 255) / 256, 256, 0, stream>>>(
        c1W, cW, cls1W, clsW, c1eW, ceW, wt1, wtc, wtcls1, wtcls, ewt1, ewtc);

    const int NEB = N_EDGES / EPB;        // 6250
    const int GRID_LIN = (N_NODES + 63) / 64;  // 782

    // ---- conv1: x [N,64] f32 -> h1 [N,128] ----
    hipMemsetAsync(t32, 0, (size_t)N_NODES * 64 * 4, stream);
    edge_mfma_kernel<64, true><<<NEB, 256, 0, stream>>>(
        x, 64, eas, srcs, dsts, ewt1, c1eb, t32);
    mfma_lin_kernel<64, 128, 2, 2, 2, 4, ACT_BN_DL, 1><<<GRID_LIN, 256, 0, stream>>>(
        x, 64, t32, wt1, c1b, c1g, c1be, h1, 128);

    // ---- conv layers 0..3 -> concat slices ----
    for (int i = 0; i < 4; ++i) {
        const void* hin = (i == 0) ? (const void*)h1 : (const void*)(concat + (size_t)(i - 1) * 128);
        int ld = (i == 0) ? 128 : 640;
        hipMemsetAsync(t32, 0, (size_t)N_NODES * 128 * 4, stream);
        edge_mfma_kernel<128, false><<<NEB, 256, 0, stream>>>(
            hin, ld, eas, srcs, dsts, ewtc + (size_t)i * 2048, ceb + (size_t)i * 128, t32);
        mfma_lin_kernel<128, 128, 2, 2, 2, 4, ACT_BN_DL, 2><<<GRID_LIN, 256, 0, stream>>>(
            hin, ld, t32, wtc + (size_t)i * 16384, cb + i * 128,
            cg + i * 128, cbe + i * 128, concat + (size_t)i * 128, 640);
    }

    // ---- global add pool (cols 384..511) -> cols 512..639 ----
    pool_add_kernel<<<(N_NODES * 128 + 255) / 256, 256, 0, stream>>>(concat, batch, pool);
    pool_gather_kernel<<<(N_NODES * 128 + 255) / 256, 256, 0, stream>>>(concat, batch, pool);

    // ---- classifier ----
    mfma_lin_kernel<640, 256, 1, 4, 4, 4, ACT_NONE, 0><<<GRID_LIN, 256, 0, stream>>>(
        concat, 640, nullptr, wtcls1, cls1b, nullptr, nullptr, clsA, 256);
    mfma_lin_kernel<256, 256, 1, 4, 4, 4, ACT_LEAKY, 0><<<GRID_LIN, 256, 0, stream>>>(
        clsA, 256, nullptr, wtcls, clsb, nullptr, nullptr, clsB, 256);
    mfma_lin_kernel<256, 256, 1, 4, 4, 4, ACT_LEAKY, 0><<<GRID_LIN, 256, 0, stream>>>(
        clsB, 256, nullptr, wtcls + 256 * 256, clsb + 256, nullptr, nullptr, clsA, 256);
    final_kernel<<<N_NODES / 4, 256, 0, stream>>>(clsA, fW, fb, out);
}